// Round 12
// baseline (158.711 us; speedup 1.0000x reference)
//
#include <hip/hip_runtime.h>
#include <math.h>

#define NBUCKETS 65536
#define EPS 1e-12

typedef float v4f __attribute__((ext_vector_type(4)));
typedef int v4i __attribute__((ext_vector_type(4)));
typedef unsigned int v4u __attribute__((ext_vector_type(4)));

// ---------------- main path: 128 chunks x 2 halves = 256 wgs (1 per CU) ----------------
// R10: 2 wg/CU regressed (FETCH doubled). R11: deeper per-wave ILP neutral.
// Scatter is pinned by the per-item predicated-LDS-atomic path; this round
// drops the NT hint on input loads (possible latency-path throttle) as the
// last cheap lever.
#define NCHUNK 128          // input chunks
#define WGT 1024
#define RROUNDS 16          // v4 loads per thread -> 64 items/thread/chunk
#define PBUCK 32768         // buckets per half (128 KB LDS -> 1 wg/CU)
#define SCALE_F 131072.0f   // 2^17 fixed point
#define INV_SCALE (1.0 / 131072.0)
#define SUM_MASK 0x0FFFFFFFu

// ws layout
#define OFF_HIST 0                                          // 128*65536*4 = 32 MB
#define OFF_SD   (NCHUNK * NBUCKETS * 4)                    // 33554432, 64K doubles
#define OFF_M    (OFF_SD + NBUCKETS * 8)                    // 34078720, 64K u32
#define OFF_CS   (OFF_M + NBUCKETS * 4)                     // 34340864, 256 doubles
#define OFF_SX   (OFF_CS + 256 * 8)                         // 34342912, 128 floats
#define OFF_CTRL (OFF_SX + NCHUNK * 4)                      // 34343424, 64 B control
#define REQ_NEW  (OFF_CTRL + 64)
// ctrl: [0]=block counter, [2..3]=nll_total (double at byte 8), [4]=nev_total

// old (fallback) ws layout
#define NREP 8
#define OSCALE_F 1073741824.0f
#define OINV_SCALE (1.0 / 1073741824.0)
#define LOW48 ((1ull << 48) - 1)
#define O_REP 0
#define O_SD (NREP * NBUCKETS * 8)
#define O_M (O_SD + NBUCKETS * 8)
#define O_CS (O_M + NBUCKETS * 4)
#define O_NLL (O_CS + 256 * 8)
#define O_NEV (O_NLL + 256 * 8)
#define O_SX (O_NEV + 256 * 4)
#define REQ_OLD (O_SX + 8192 * 4)

__device__ __forceinline__ unsigned int xcd_id() {
    unsigned int x;
    asm volatile("s_getreg_b32 %0, hwreg(HW_REG_XCC_ID)" : "=s"(x));
    return x & 7u;
}

// ------------- scatter: 256 wgs = (chunk, bucket-half); stream -> LDS atomics -> slab -------------
// NO per-item register stash (R5/6: 64-reg array spilled to scratch, 25x loss).
// Plain (non-NT) input loads this round; NT kept on histogram write-out.
__global__ __launch_bounds__(WGT) void scatter_half_kernel(
        const v4f* __restrict__ x4, const v4i* __restrict__ e4,
        const v4i* __restrict__ t4, unsigned int* __restrict__ hist,
        float* __restrict__ sum_ex_part, int n4,
        const float* __restrict__ x_s, const int* __restrict__ e_s,
        const int* __restrict__ t_s, int tail_base, int tail_cnt) {
    __shared__ unsigned int lds[PBUCK];
    const int t = threadIdx.x;
    const int wg = blockIdx.x;
    const int half = wg & 1;
    const int chunk = wg >> 1;
    const unsigned int uh = (unsigned int)half;

    // zero the LDS histogram
    v4u* lds4 = (v4u*)lds;
#pragma unroll
    for (int q = 0; q < PBUCK / 4 / WGT; q++)
        lds4[t + q * WGT] = (v4u){0u, 0u, 0u, 0u};
    __syncthreads();

    float ev_x = 0.0f;

#pragma unroll 1
    for (int r = 0; r < RROUNDS; r++) {
        int idx = (chunk * RROUNDS + r) * WGT + t;
        if (idx < n4) {
            v4f x = x4[idx];
            v4i e = e4[idx];
            v4i tm = t4[idx];
#pragma unroll
            for (int k = 0; k < 4; k++) {
                float xv = x[k];
                unsigned int b = (unsigned int)tm[k] & 0xFFFFu;
                unsigned int ev = (e[k] != 0) ? 1u : 0u;
                if ((b >> 15) == uh) {
                    unsigned int pk = (ev << 28) +
                                      (unsigned int)(expf(xv) * SCALE_F + 0.5f);
                    atomicAdd(&lds[b & (PBUCK - 1)], pk);
                }
                if (half == 0 && ev) ev_x += xv;  // sum_ex counted once (half 0)
            }
        }
    }

    // N%4 tail: both halves of chunk 0 check it (each keeps matching buckets)
    if (chunk == 0 && t == 0 && tail_cnt > 0) {
        for (int i = 0; i < tail_cnt; i++) {
            int idx = tail_base + i;
            float xv = x_s[idx];
            unsigned int b = (unsigned int)t_s[idx] & 0xFFFFu;
            unsigned int ev = (e_s[idx] != 0) ? 1u : 0u;
            if ((b >> 15) == uh) {
                unsigned int pk = (ev << 28) +
                                  (unsigned int)(expf(xv) * SCALE_F + 0.5f);
                atomicAdd(&lds[b & (PBUCK - 1)], pk);
            }
            if (half == 0 && ev) ev_x += xv;
        }
    }
    __syncthreads();

    // coalesced write-out of this half's 32K-bucket slab
    v4u* hbase = (v4u*)(hist + (size_t)chunk * NBUCKETS + (size_t)half * PBUCK);
#pragma unroll
    for (int q = 0; q < PBUCK / 4 / WGT; q++) {
        v4u v = lds4[t + q * WGT];
        __builtin_nontemporal_store(v, &hbase[t + q * WGT]);
    }

    // sum_ex partial (half 0 only): wave reduce, then cross-wave via LDS
    if (half == 0) {
        __syncthreads();
#pragma unroll
        for (int off = 32; off > 0; off >>= 1) ev_x += __shfl_down(ev_x, off, 64);
        if ((t & 63) == 0) lds[t >> 6] = __float_as_uint(ev_x);
        __syncthreads();
        if (t == 0) {
            float s = 0.0f;
            for (int w = 0; w < WGT / 64; w++) s += __uint_as_float(lds[w]);
            sum_ex_part[chunk] = s;
        }
    }
}

// ------------- tail: merge (256 blocks) then fused suffix+final (256 blocks) -------------
// merge: block b owns buckets [b*256, b*256+256); wave tg reduces slabs
// [tg*32, tg*32+32) with v4u reads. Also zeroes ctrl for the next kernel.
__global__ __launch_bounds__(256) void merge_chunk_kernel(
        const v4u* __restrict__ hist4, double* __restrict__ Sd,
        unsigned int* __restrict__ m, double* __restrict__ chunk_sum,
        unsigned int* __restrict__ ctrl) {
    const int t = threadIdx.x, b = blockIdx.x;
    const int tg = t >> 6, lane = t & 63;

    if (b == 0 && t == 0) {
        ctrl[0] = 0u;
        ((double*)ctrl)[1] = 0.0;
        ctrl[4] = 0u;
    }

    unsigned long long s[4] = {0ull, 0ull, 0ull, 0ull};
    unsigned int c[4] = {0u, 0u, 0u, 0u};
    const v4u* base = hist4 + (size_t)(tg * (NCHUNK / 4)) * (NBUCKETS / 4) +
                      (size_t)b * 64 + lane;
#pragma unroll 4
    for (int w = 0; w < NCHUNK / 4; w++) {
        v4u h = base[(size_t)w * (NBUCKETS / 4)];
#pragma unroll
        for (int q = 0; q < 4; q++) {
            s[q] += (unsigned long long)(h[q] & SUM_MASK);
            c[q] += h[q] >> 28;
        }
    }
    __shared__ unsigned long long lsum[4][64][4];
    __shared__ unsigned int lcnt[4][64][4];
#pragma unroll
    for (int q = 0; q < 4; q++) { lsum[tg][lane][q] = s[q]; lcnt[tg][lane][q] = c[q]; }
    __syncthreads();

    // bucket b*256 + t  <->  (lane2 = t>>2, comp = t&3)  [verified: absmax 0 R8-R11]
    unsigned long long Ssum = lsum[0][t >> 2][t & 3] + lsum[1][t >> 2][t & 3] +
                              lsum[2][t >> 2][t & 3] + lsum[3][t >> 2][t & 3];
    unsigned int M = lcnt[0][t >> 2][t & 3] + lcnt[1][t >> 2][t & 3] +
                     lcnt[2][t >> 2][t & 3] + lcnt[3][t >> 2][t & 3];
    double sv = (double)Ssum * INV_SCALE;
    Sd[b * 256 + t] = sv;
    m[b * 256 + t] = M;

    __shared__ double red[256];
    red[t] = sv;
    __syncthreads();
    for (int st = 128; st > 0; st >>= 1) {
        if (t < st) red[t] += red[t + st];
        __syncthreads();
    }
    if (t == 0) chunk_sum[b] = red[0];
}

// fused suffix + final: per-block suffix scan + nll; device-atomic accumulate;
// LAST block (atomic counter, no spin-wait) reduces sum_ex and writes out.
__global__ __launch_bounds__(256) void suffix_final_kernel(
        const double* __restrict__ Sd, const unsigned int* __restrict__ m,
        const double* __restrict__ chunk_sum, const float* __restrict__ sum_ex_part,
        unsigned int* __restrict__ ctrl, float* __restrict__ out) {
    __shared__ double cs[256];
    __shared__ double sfx[256];
    __shared__ unsigned int ured[256];
    __shared__ int lastblk;
    const int t = threadIdx.x;
    const int b = blockIdx.x;

    cs[t] = (t > b) ? chunk_sum[t] : 0.0;
    __syncthreads();
    for (int s = 128; s > 0; s >>= 1) {
        if (t < s) cs[t] += cs[t + s];
        __syncthreads();
    }
    double offset = cs[0];
    __syncthreads();

    int i = b * 256 + t;
    double sv = Sd[i];
    unsigned int mv = m[i];

    sfx[t] = sv;
    __syncthreads();
    for (int s = 1; s < 256; s <<= 1) {
        double add = (t + s < 256) ? sfx[t + s] : 0.0;
        __syncthreads();
        sfx[t] += add;
        __syncthreads();
    }

    double denom = offset + sfx[t] + EPS;
    double nll = (mv != 0u) ? (double)mv * log(denom) : 0.0;

    cs[t] = nll;
    ured[t] = mv;
    __syncthreads();
    for (int s = 128; s > 0; s >>= 1) {
        if (t < s) { cs[t] += cs[t + s]; ured[t] += ured[t + s]; }
        __syncthreads();
    }
    if (t == 0) {
        atomicAdd((double*)ctrl + 1, cs[0]);
        atomicAdd(&ctrl[4], ured[0]);
        __threadfence();
        unsigned int old = __hip_atomic_fetch_add(&ctrl[0], 1u, __ATOMIC_ACQ_REL,
                                                  __HIP_MEMORY_SCOPE_AGENT);
        lastblk = (old == (unsigned)gridDim.x - 1) ? 1 : 0;
    }
    __syncthreads();
    if (lastblk) {
        cs[t] = (t < NCHUNK) ? (double)sum_ex_part[t] : 0.0;
        __syncthreads();
        for (int s = 128; s > 0; s >>= 1) {
            if (t < s) cs[t] += cs[t + s];
            __syncthreads();
        }
        if (t == 0) {
            double nllT = __hip_atomic_load((double*)ctrl + 1, __ATOMIC_RELAXED,
                                            __HIP_MEMORY_SCOPE_AGENT);
            unsigned int nev = __hip_atomic_load(&ctrl[4], __ATOMIC_RELAXED,
                                                 __HIP_MEMORY_SCOPE_AGENT);
            out[0] = (float)((nllT - cs[0]) / ((double)nev + EPS));
        }
    }
}

// ------------------------- old (fallback) path kernels -------------------------
__global__ void zero_ws_kernel(unsigned long long* __restrict__ rep, int n) {
    int i = blockIdx.x * blockDim.x + threadIdx.x;
    if (i < n) rep[i] = 0ull;
}

__global__ __launch_bounds__(256) void scatter_atomic_kernel(
        const v4f* __restrict__ x4, const v4i* __restrict__ e4,
        const v4i* __restrict__ t4,
        unsigned long long* __restrict__ rep, float* __restrict__ sum_ex_part,
        int n4, const float* __restrict__ x_s, const int* __restrict__ e_s,
        const int* __restrict__ t_s, int tail_base, int tail_cnt) {
    int i = blockIdx.x * blockDim.x + threadIdx.x;
    unsigned long long* R = rep + (size_t)xcd_id() * NBUCKETS;
    float ev_x = 0.0f;
    if (i < n4) {
        v4f x = x4[i];
        v4i e = e4[i];
        v4i t = t4[i];
#pragma unroll
        for (int k = 0; k < 4; k++) {
            float xv = x[k];
            unsigned int v = (unsigned int)t[k] & 0xFFFFu;
            unsigned long long pk =
                ((unsigned long long)(e[k] != 0) << 48) +
                (unsigned long long)(expf(xv) * OSCALE_F + 0.5f);
            __hip_atomic_fetch_add(&R[v], pk, __ATOMIC_RELAXED,
                                   __HIP_MEMORY_SCOPE_WORKGROUP);
            if (e[k]) ev_x += xv;
        }
    }
    if (i < tail_cnt) {
        int idx = tail_base + i;
        float xv = x_s[idx];
        unsigned int v = (unsigned int)t_s[idx] & 0xFFFFu;
        unsigned long long pk =
            ((unsigned long long)(e_s[idx] != 0) << 48) +
            (unsigned long long)(expf(xv) * OSCALE_F + 0.5f);
        __hip_atomic_fetch_add(&R[v], pk, __ATOMIC_RELAXED,
                               __HIP_MEMORY_SCOPE_WORKGROUP);
        if (e_s[idx]) ev_x += xv;
    }
    __shared__ float sred[256];
    sred[threadIdx.x] = ev_x;
    __syncthreads();
    for (int s = 128; s > 0; s >>= 1) {
        if ((int)threadIdx.x < s) sred[threadIdx.x] += sred[threadIdx.x + s];
        __syncthreads();
    }
    if (threadIdx.x == 0) sum_ex_part[blockIdx.x] = sred[0];
}

__global__ __launch_bounds__(256) void reduce_kernel(
        const unsigned long long* __restrict__ rep, double* __restrict__ Sd,
        unsigned int* __restrict__ m, double* __restrict__ chunk_sum) {
    int t = threadIdx.x;
    int i = blockIdx.x * 256 + t;
    unsigned long long acc = 0ull;
#pragma unroll
    for (int r = 0; r < NREP; r++) acc += rep[(size_t)r * NBUCKETS + i];
    double sv = (double)(acc & LOW48) * OINV_SCALE;
    unsigned int mv = (unsigned int)(acc >> 48);
    Sd[i] = sv;
    m[i] = mv;
    __shared__ double red[256];
    red[t] = sv;
    __syncthreads();
    for (int s = 128; s > 0; s >>= 1) {
        if (t < s) red[t] += red[t + s];
        __syncthreads();
    }
    if (t == 0) chunk_sum[blockIdx.x] = red[0];
}

__global__ __launch_bounds__(256) void suffix_kernel(
        const double* __restrict__ Sd, const unsigned int* __restrict__ m,
        const double* __restrict__ chunk_sum, double* __restrict__ nll_part,
        unsigned int* __restrict__ nev_part) {
    __shared__ double cs[256];
    __shared__ double sfx[256];
    __shared__ unsigned int ured[256];
    const int t = threadIdx.x;
    const int b = blockIdx.x;

    cs[t] = (t > b) ? chunk_sum[t] : 0.0;
    __syncthreads();
    for (int s = 128; s > 0; s >>= 1) {
        if (t < s) cs[t] += cs[t + s];
        __syncthreads();
    }
    double offset = cs[0];
    __syncthreads();

    int i = b * 256 + t;
    double sv = Sd[i];
    unsigned int mv = m[i];

    sfx[t] = sv;
    __syncthreads();
    for (int s = 1; s < 256; s <<= 1) {
        double add = (t + s < 256) ? sfx[t + s] : 0.0;
        __syncthreads();
        sfx[t] += add;
        __syncthreads();
    }

    double denom = offset + sfx[t] + EPS;
    double nll = (mv != 0u) ? (double)mv * log(denom) : 0.0;

    cs[t] = nll;
    ured[t] = mv;
    __syncthreads();
    for (int s = 128; s > 0; s >>= 1) {
        if (t < s) { cs[t] += cs[t + s]; ured[t] += ured[t + s]; }
        __syncthreads();
    }
    if (t == 0) {
        nll_part[b] = cs[0];
        nev_part[b] = ured[0];
    }
}

__global__ __launch_bounds__(256) void final_kernel(
        const double* __restrict__ nll_part, const unsigned int* __restrict__ nev_part,
        const float* __restrict__ sum_ex_part, int n_sx, float* __restrict__ out) {
    __shared__ double rd[256];
    __shared__ double rs[256];
    __shared__ unsigned int ru[256];
    int t = threadIdx.x;
    double nll = nll_part[t];
    unsigned int ne = nev_part[t];
    double sx = 0.0;
    for (int i = t; i < n_sx; i += 256) sx += (double)sum_ex_part[i];
    rd[t] = nll;
    rs[t] = sx;
    ru[t] = ne;
    __syncthreads();
    for (int s = 128; s > 0; s >>= 1) {
        if (t < s) { rd[t] += rd[t + s]; rs[t] += rs[t + s]; ru[t] += ru[t + s]; }
        __syncthreads();
    }
    if (t == 0) {
        double total = rd[0] - rs[0];
        out[0] = (float)(total / ((double)ru[0] + EPS));
    }
}

extern "C" void kernel_launch(void* const* d_in, const int* in_sizes, int n_in,
                              void* d_out, int out_size, void* d_ws, size_t ws_size,
                              hipStream_t stream) {
    const float* logits = (const float*)d_in[0];
    const int* status = (const int*)d_in[1];
    const int* time = (const int*)d_in[2];
    const int N = in_sizes[0];

    char* ws = (char*)d_ws;
    int n4 = N / 4;
    int tail_base = n4 * 4;
    int tail_cnt = N - tail_base;

    if (ws_size >= (size_t)REQ_NEW && N <= NCHUNK * WGT * RROUNDS * 4) {
        unsigned int* hist = (unsigned int*)(ws + OFF_HIST);
        double* Sd = (double*)(ws + OFF_SD);
        unsigned int* m = (unsigned int*)(ws + OFF_M);
        double* chunk_sum = (double*)(ws + OFF_CS);
        float* sum_ex_part = (float*)(ws + OFF_SX);
        unsigned int* ctrl = (unsigned int*)(ws + OFF_CTRL);

        scatter_half_kernel<<<NCHUNK * 2, WGT, 0, stream>>>(
            (const v4f*)logits, (const v4i*)status, (const v4i*)time,
            hist, sum_ex_part, n4, logits, status, time, tail_base, tail_cnt);
        merge_chunk_kernel<<<256, 256, 0, stream>>>((const v4u*)hist, Sd, m,
                                                    chunk_sum, ctrl);
        suffix_final_kernel<<<256, 256, 0, stream>>>(Sd, m, chunk_sum, sum_ex_part,
                                                     ctrl, (float*)d_out);
    } else {
        unsigned long long* rep = (unsigned long long*)(ws + O_REP);
        double* Sd = (double*)(ws + O_SD);
        unsigned int* m = (unsigned int*)(ws + O_M);
        double* chunk_sum = (double*)(ws + O_CS);
        double* nll_part = (double*)(ws + O_NLL);
        unsigned int* nev_part = (unsigned int*)(ws + O_NEV);
        float* sum_ex_part = (float*)(ws + O_SX);

        int nrep_total = NREP * NBUCKETS;
        zero_ws_kernel<<<(nrep_total + 255) / 256, 256, 0, stream>>>(rep, nrep_total);
        int blocks = (n4 + 255) / 256;
        if (blocks < 1) blocks = 1;
        scatter_atomic_kernel<<<blocks, 256, 0, stream>>>(
            (const v4f*)logits, (const v4i*)status, (const v4i*)time,
            rep, sum_ex_part, n4, logits, status, time, tail_base, tail_cnt);
        reduce_kernel<<<256, 256, 0, stream>>>(rep, Sd, m, chunk_sum);
        suffix_kernel<<<256, 256, 0, stream>>>(Sd, m, chunk_sum, nll_part, nev_part);
        final_kernel<<<1, 256, 0, stream>>>(nll_part, nev_part, sum_ex_part, blocks,
                                            (float*)d_out);
    }
}

// Round 13
// 154.326 us; speedup vs baseline: 1.0284x; 1.0284x over previous
//
#include <hip/hip_runtime.h>
#include <math.h>

#define NBUCKETS 65536
#define EPS 1e-12

typedef float v4f __attribute__((ext_vector_type(4)));
typedef int v4i __attribute__((ext_vector_type(4)));
typedef unsigned int v4u __attribute__((ext_vector_type(4)));

// ---------------- main path: 128 chunks x 2 halves = 256 wgs (1 per CU) ----------------
// Final configuration = R9's empirical optimum (154.2 us total):
//   - NT input loads (R12 showed removing NT was neutral-to-worse)
//   - 2-deep prefetch NOT used (R11: neutral; compiler already pipelines)
//   - 1 wg/CU, 128 KB LDS (R10: 2 wg/CU regressed, FETCH doubled)
//   - split 3-kernel tail (R8: fused spin-barrier tail ran 42 us vs ~6)
// Scatter plateau evidence (R9-R12): VALU ~24%, HBM 3.2/6.3 TB/s, no saturated
// pipe; occupancy/ILP/cache-policy levers all neutral or regressive. The
// 2-visits-per-item cost is structural: 64K buckets x 4B = 256 KB > 160 KB LDS.
#define NCHUNK 128          // input chunks
#define WGT 1024
#define RROUNDS 16          // v4 loads per thread -> 64 items/thread/chunk
#define PBUCK 32768         // buckets per half (128 KB LDS -> 1 wg/CU)
#define SCALE_F 131072.0f   // 2^17 fixed point
#define INV_SCALE (1.0 / 131072.0)
#define SUM_MASK 0x0FFFFFFFu

// ws layout
#define OFF_HIST 0                                          // 128*65536*4 = 32 MB
#define OFF_SD   (NCHUNK * NBUCKETS * 4)                    // 33554432, 64K doubles
#define OFF_M    (OFF_SD + NBUCKETS * 8)                    // 34078720, 64K u32
#define OFF_CS   (OFF_M + NBUCKETS * 4)                     // 34340864, 256 doubles
#define OFF_NLL  (OFF_CS + 256 * 8)                         // 34342912, 256 doubles
#define OFF_NEV  (OFF_NLL + 256 * 8)                        // 34344960, 256 u32
#define OFF_SX   (OFF_NEV + 256 * 4)                        // 34345984, 128 floats
#define REQ_NEW  (OFF_SX + NCHUNK * 4)

// old (fallback) ws layout
#define NREP 8
#define OSCALE_F 1073741824.0f
#define OINV_SCALE (1.0 / 1073741824.0)
#define LOW48 ((1ull << 48) - 1)
#define O_REP 0
#define O_SD (NREP * NBUCKETS * 8)
#define O_M (O_SD + NBUCKETS * 8)
#define O_CS (O_M + NBUCKETS * 4)
#define O_NLL (O_CS + 256 * 8)
#define O_NEV (O_NLL + 256 * 8)
#define O_SX (O_NEV + 256 * 4)
#define REQ_OLD (O_SX + 8192 * 4)

__device__ __forceinline__ unsigned int xcd_id() {
    unsigned int x;
    asm volatile("s_getreg_b32 %0, hwreg(HW_REG_XCC_ID)" : "=s"(x));
    return x & 7u;
}

// ------------- scatter: 256 wgs = (chunk, bucket-half); stream -> LDS atomics -> slab -------------
// NO per-item register stash: rounds 5/6 showed the allocator pins VGPR=64 and
// spills a 64-reg stash to scratch (1.5 GB fetch, 25x slowdown) regardless of
// __launch_bounds__ hints. Each wg streams its chunk and filters to its bucket
// half; the chunk's other-half twin wg runs concurrently, so the second read is
// Infinity-Cache-resident (R8/R9: FETCH == one read of the input).
__global__ __launch_bounds__(WGT) void scatter_half_kernel(
        const v4f* __restrict__ x4, const v4i* __restrict__ e4,
        const v4i* __restrict__ t4, unsigned int* __restrict__ hist,
        float* __restrict__ sum_ex_part, int n4,
        const float* __restrict__ x_s, const int* __restrict__ e_s,
        const int* __restrict__ t_s, int tail_base, int tail_cnt) {
    __shared__ unsigned int lds[PBUCK];
    const int t = threadIdx.x;
    const int wg = blockIdx.x;
    const int half = wg & 1;
    const int chunk = wg >> 1;
    const unsigned int uh = (unsigned int)half;

    // zero the LDS histogram
    v4u* lds4 = (v4u*)lds;
#pragma unroll
    for (int q = 0; q < PBUCK / 4 / WGT; q++)
        lds4[t + q * WGT] = (v4u){0u, 0u, 0u, 0u};
    __syncthreads();

    float ev_x = 0.0f;

#pragma unroll 1
    for (int r = 0; r < RROUNDS; r++) {
        int idx = (chunk * RROUNDS + r) * WGT + t;
        if (idx < n4) {
            v4f x = __builtin_nontemporal_load(&x4[idx]);
            v4i e = __builtin_nontemporal_load(&e4[idx]);
            v4i tm = __builtin_nontemporal_load(&t4[idx]);
#pragma unroll
            for (int k = 0; k < 4; k++) {
                float xv = x[k];
                unsigned int b = (unsigned int)tm[k] & 0xFFFFu;
                unsigned int ev = (e[k] != 0) ? 1u : 0u;
                if ((b >> 15) == uh) {
                    unsigned int pk = (ev << 28) +
                                      (unsigned int)(expf(xv) * SCALE_F + 0.5f);
                    atomicAdd(&lds[b & (PBUCK - 1)], pk);
                }
                if (half == 0 && ev) ev_x += xv;  // sum_ex counted once (half 0)
            }
        }
    }

    // N%4 tail: both halves of chunk 0 check it (each keeps matching buckets)
    if (chunk == 0 && t == 0 && tail_cnt > 0) {
        for (int i = 0; i < tail_cnt; i++) {
            int idx = tail_base + i;
            float xv = x_s[idx];
            unsigned int b = (unsigned int)t_s[idx] & 0xFFFFu;
            unsigned int ev = (e_s[idx] != 0) ? 1u : 0u;
            if ((b >> 15) == uh) {
                unsigned int pk = (ev << 28) +
                                  (unsigned int)(expf(xv) * SCALE_F + 0.5f);
                atomicAdd(&lds[b & (PBUCK - 1)], pk);
            }
            if (half == 0 && ev) ev_x += xv;
        }
    }
    __syncthreads();

    // coalesced write-out of this half's 32K-bucket slab
    v4u* hbase = (v4u*)(hist + (size_t)chunk * NBUCKETS + (size_t)half * PBUCK);
#pragma unroll
    for (int q = 0; q < PBUCK / 4 / WGT; q++) {
        v4u v = lds4[t + q * WGT];
        __builtin_nontemporal_store(v, &hbase[t + q * WGT]);
    }

    // sum_ex partial (half 0 only): wave reduce, then cross-wave via LDS
    if (half == 0) {
        __syncthreads();
#pragma unroll
        for (int off = 32; off > 0; off >>= 1) ev_x += __shfl_down(ev_x, off, 64);
        if ((t & 63) == 0) lds[t >> 6] = __float_as_uint(ev_x);
        __syncthreads();
        if (t == 0) {
            float s = 0.0f;
            for (int w = 0; w < WGT / 64; w++) s += __uint_as_float(lds[w]);
            sum_ex_part[chunk] = s;
        }
    }
}

// ------------- split tail (R4/R9-proven structure; NO grid barrier — R8's fused
// spin-barrier version ran ~42 us vs ~6 for the split) -------------
// merge: 256 blocks x 256 threads; block b owns buckets [b*256, b*256+256).
// wave tg reduces slabs [tg*32, tg*32+32) with v4u reads (1 KB/wave/instr).
__global__ __launch_bounds__(256) void merge_chunk_kernel(
        const v4u* __restrict__ hist4, double* __restrict__ Sd,
        unsigned int* __restrict__ m, double* __restrict__ chunk_sum) {
    const int t = threadIdx.x, b = blockIdx.x;
    const int tg = t >> 6, lane = t & 63;

    unsigned long long s[4] = {0ull, 0ull, 0ull, 0ull};
    unsigned int c[4] = {0u, 0u, 0u, 0u};
    const v4u* base = hist4 + (size_t)(tg * (NCHUNK / 4)) * (NBUCKETS / 4) +
                      (size_t)b * 64 + lane;
#pragma unroll 4
    for (int w = 0; w < NCHUNK / 4; w++) {
        v4u h = base[(size_t)w * (NBUCKETS / 4)];
#pragma unroll
        for (int q = 0; q < 4; q++) {
            s[q] += (unsigned long long)(h[q] & SUM_MASK);
            c[q] += h[q] >> 28;
        }
    }
    __shared__ unsigned long long lsum[4][64][4];
    __shared__ unsigned int lcnt[4][64][4];
#pragma unroll
    for (int q = 0; q < 4; q++) { lsum[tg][lane][q] = s[q]; lcnt[tg][lane][q] = c[q]; }
    __syncthreads();

    // bucket b*256 + t  <->  (lane2 = t>>2, comp = t&3)  [verified: absmax 0 R8-R12]
    unsigned long long Ssum = lsum[0][t >> 2][t & 3] + lsum[1][t >> 2][t & 3] +
                              lsum[2][t >> 2][t & 3] + lsum[3][t >> 2][t & 3];
    unsigned int M = lcnt[0][t >> 2][t & 3] + lcnt[1][t >> 2][t & 3] +
                     lcnt[2][t >> 2][t & 3] + lcnt[3][t >> 2][t & 3];
    double sv = (double)Ssum * INV_SCALE;
    Sd[b * 256 + t] = sv;
    m[b * 256 + t] = M;

    __shared__ double red[256];
    red[t] = sv;
    __syncthreads();
    for (int st = 128; st > 0; st >>= 1) {
        if (t < st) red[t] += red[t + st];
        __syncthreads();
    }
    if (t == 0) chunk_sum[b] = red[0];
}

__global__ __launch_bounds__(256) void suffix_kernel(
        const double* __restrict__ Sd, const unsigned int* __restrict__ m,
        const double* __restrict__ chunk_sum, double* __restrict__ nll_part,
        unsigned int* __restrict__ nev_part) {
    __shared__ double cs[256];
    __shared__ double sfx[256];
    __shared__ unsigned int ured[256];
    const int t = threadIdx.x;
    const int b = blockIdx.x;

    cs[t] = (t > b) ? chunk_sum[t] : 0.0;
    __syncthreads();
    for (int s = 128; s > 0; s >>= 1) {
        if (t < s) cs[t] += cs[t + s];
        __syncthreads();
    }
    double offset = cs[0];
    __syncthreads();

    int i = b * 256 + t;
    double sv = Sd[i];
    unsigned int mv = m[i];

    sfx[t] = sv;
    __syncthreads();
    for (int s = 1; s < 256; s <<= 1) {
        double add = (t + s < 256) ? sfx[t + s] : 0.0;
        __syncthreads();
        sfx[t] += add;
        __syncthreads();
    }

    double denom = offset + sfx[t] + EPS;
    double nll = (mv != 0u) ? (double)mv * log(denom) : 0.0;

    cs[t] = nll;
    ured[t] = mv;
    __syncthreads();
    for (int s = 128; s > 0; s >>= 1) {
        if (t < s) { cs[t] += cs[t + s]; ured[t] += ured[t + s]; }
        __syncthreads();
    }
    if (t == 0) {
        nll_part[b] = cs[0];
        nev_part[b] = ured[0];
    }
}

__global__ __launch_bounds__(256) void final_kernel(
        const double* __restrict__ nll_part, const unsigned int* __restrict__ nev_part,
        const float* __restrict__ sum_ex_part, int n_sx, float* __restrict__ out) {
    __shared__ double rd[256];
    __shared__ double rs[256];
    __shared__ unsigned int ru[256];
    int t = threadIdx.x;
    double nll = nll_part[t];
    unsigned int ne = nev_part[t];
    double sx = 0.0;
    for (int i = t; i < n_sx; i += 256) sx += (double)sum_ex_part[i];
    rd[t] = nll;
    rs[t] = sx;
    ru[t] = ne;
    __syncthreads();
    for (int s = 128; s > 0; s >>= 1) {
        if (t < s) { rd[t] += rd[t + s]; rs[t] += rs[t + s]; ru[t] += ru[t + s]; }
        __syncthreads();
    }
    if (t == 0) {
        double total = rd[0] - rs[0];
        out[0] = (float)(total / ((double)ru[0] + EPS));
    }
}

// ------------------------- old (fallback) path kernels -------------------------
__global__ void zero_ws_kernel(unsigned long long* __restrict__ rep, int n) {
    int i = blockIdx.x * blockDim.x + threadIdx.x;
    if (i < n) rep[i] = 0ull;
}

__global__ __launch_bounds__(256) void scatter_atomic_kernel(
        const v4f* __restrict__ x4, const v4i* __restrict__ e4,
        const v4i* __restrict__ t4,
        unsigned long long* __restrict__ rep, float* __restrict__ sum_ex_part,
        int n4, const float* __restrict__ x_s, const int* __restrict__ e_s,
        const int* __restrict__ t_s, int tail_base, int tail_cnt) {
    int i = blockIdx.x * blockDim.x + threadIdx.x;
    unsigned long long* R = rep + (size_t)xcd_id() * NBUCKETS;
    float ev_x = 0.0f;
    if (i < n4) {
        v4f x = __builtin_nontemporal_load(&x4[i]);
        v4i e = __builtin_nontemporal_load(&e4[i]);
        v4i t = __builtin_nontemporal_load(&t4[i]);
#pragma unroll
        for (int k = 0; k < 4; k++) {
            float xv = x[k];
            unsigned int v = (unsigned int)t[k] & 0xFFFFu;
            unsigned long long pk =
                ((unsigned long long)(e[k] != 0) << 48) +
                (unsigned long long)(expf(xv) * OSCALE_F + 0.5f);
            __hip_atomic_fetch_add(&R[v], pk, __ATOMIC_RELAXED,
                                   __HIP_MEMORY_SCOPE_WORKGROUP);
            if (e[k]) ev_x += xv;
        }
    }
    if (i < tail_cnt) {
        int idx = tail_base + i;
        float xv = x_s[idx];
        unsigned int v = (unsigned int)t_s[idx] & 0xFFFFu;
        unsigned long long pk =
            ((unsigned long long)(e_s[idx] != 0) << 48) +
            (unsigned long long)(expf(xv) * OSCALE_F + 0.5f);
        __hip_atomic_fetch_add(&R[v], pk, __ATOMIC_RELAXED,
                               __HIP_MEMORY_SCOPE_WORKGROUP);
        if (e_s[idx]) ev_x += xv;
    }
    __shared__ float sred[256];
    sred[threadIdx.x] = ev_x;
    __syncthreads();
    for (int s = 128; s > 0; s >>= 1) {
        if ((int)threadIdx.x < s) sred[threadIdx.x] += sred[threadIdx.x + s];
        __syncthreads();
    }
    if (threadIdx.x == 0) sum_ex_part[blockIdx.x] = sred[0];
}

__global__ __launch_bounds__(256) void reduce_kernel(
        const unsigned long long* __restrict__ rep, double* __restrict__ Sd,
        unsigned int* __restrict__ m, double* __restrict__ chunk_sum) {
    int t = threadIdx.x;
    int i = blockIdx.x * 256 + t;
    unsigned long long acc = 0ull;
#pragma unroll
    for (int r = 0; r < NREP; r++) acc += rep[(size_t)r * NBUCKETS + i];
    double sv = (double)(acc & LOW48) * OINV_SCALE;
    unsigned int mv = (unsigned int)(acc >> 48);
    Sd[i] = sv;
    m[i] = mv;
    __shared__ double red[256];
    red[t] = sv;
    __syncthreads();
    for (int s = 128; s > 0; s >>= 1) {
        if (t < s) red[t] += red[t + s];
        __syncthreads();
    }
    if (t == 0) chunk_sum[blockIdx.x] = red[0];
}

extern "C" void kernel_launch(void* const* d_in, const int* in_sizes, int n_in,
                              void* d_out, int out_size, void* d_ws, size_t ws_size,
                              hipStream_t stream) {
    const float* logits = (const float*)d_in[0];
    const int* status = (const int*)d_in[1];
    const int* time = (const int*)d_in[2];
    const int N = in_sizes[0];

    char* ws = (char*)d_ws;
    int n4 = N / 4;
    int tail_base = n4 * 4;
    int tail_cnt = N - tail_base;

    if (ws_size >= (size_t)REQ_NEW && N <= NCHUNK * WGT * RROUNDS * 4) {
        unsigned int* hist = (unsigned int*)(ws + OFF_HIST);
        double* Sd = (double*)(ws + OFF_SD);
        unsigned int* m = (unsigned int*)(ws + OFF_M);
        double* chunk_sum = (double*)(ws + OFF_CS);
        double* nll_part = (double*)(ws + OFF_NLL);
        unsigned int* nev_part = (unsigned int*)(ws + OFF_NEV);
        float* sum_ex_part = (float*)(ws + OFF_SX);

        scatter_half_kernel<<<NCHUNK * 2, WGT, 0, stream>>>(
            (const v4f*)logits, (const v4i*)status, (const v4i*)time,
            hist, sum_ex_part, n4, logits, status, time, tail_base, tail_cnt);
        merge_chunk_kernel<<<256, 256, 0, stream>>>((const v4u*)hist, Sd, m, chunk_sum);
        suffix_kernel<<<256, 256, 0, stream>>>(Sd, m, chunk_sum, nll_part, nev_part);
        final_kernel<<<1, 256, 0, stream>>>(nll_part, nev_part, sum_ex_part, NCHUNK,
                                            (float*)d_out);
    } else {
        unsigned long long* rep = (unsigned long long*)(ws + O_REP);
        double* Sd = (double*)(ws + O_SD);
        unsigned int* m = (unsigned int*)(ws + O_M);
        double* chunk_sum = (double*)(ws + O_CS);
        double* nll_part = (double*)(ws + O_NLL);
        unsigned int* nev_part = (unsigned int*)(ws + O_NEV);
        float* sum_ex_part = (float*)(ws + O_SX);

        int nrep_total = NREP * NBUCKETS;
        zero_ws_kernel<<<(nrep_total + 255) / 256, 256, 0, stream>>>(rep, nrep_total);
        int blocks = (n4 + 255) / 256;
        if (blocks < 1) blocks = 1;
        scatter_atomic_kernel<<<blocks, 256, 0, stream>>>(
            (const v4f*)logits, (const v4i*)status, (const v4i*)time,
            rep, sum_ex_part, n4, logits, status, time, tail_base, tail_cnt);
        reduce_kernel<<<256, 256, 0, stream>>>(rep, Sd, m, chunk_sum);
        suffix_kernel<<<256, 256, 0, stream>>>(Sd, m, chunk_sum, nll_part, nev_part);
        final_kernel<<<1, 256, 0, stream>>>(nll_part, nev_part, sum_ex_part, blocks,
                                            (float*)d_out);
    }
}